// Round 13
// baseline (259.260 us; speedup 1.0000x reference)
//
#include <hip/hip_runtime.h>

// AdaptiveEmbedding: VOCAB=50000, cutoffs [20000,40000], EMBED_DIM=1024, pad=1
// cluster 0: ids [0,20000)     -> emb0 [20000,1024], direct f32 gather
// cluster 1: ids [20000,40000) -> emb1 [20000,256]  @ proj1[1024,256]^T  (bf16 MFMA)
// cluster 2: ids [40000,50000) -> emb2 [10000,64]   @ proj2[1024,64]^T   (bf16 MFMA)
//
// Round 13: MEGAKERNEL. cvt_k pre-converts proj->bf16 fragment order (3us),
// then mega_k: each block owns 64 consecutive tokens, classifies them
// BLOCK-LOCALLY in LDS (no global atomics, no lists, no memset, no classify
// kernel), then: copy cluster-0 rows, MFMA-gemm the cluster-1/2 tokens in
// 32-token subtiles (r12's proven staging/MFMA/C-LDS-stage code).

constexpr int NTOK = 8 * 4096;
constexpr int C1 = 20000;
constexpr int C2 = 40000;
constexpr int DIM = 1024;
constexpr int PAD = 1;
constexpr int K1 = 256, K2 = 64;
constexpr int NP1 = DIM * K1;
constexpr int NP2 = DIM * K2;
constexpr int TPB = 64;              // tokens per block
constexpr int NBLK = NTOK / TPB;     // 512 blocks -> 2/CU
constexpr int CROW = DIM + 4;        // C-tile row stride (words): 2-way alias only
constexpr int SMEM_BYTES = 16 * CROW * 4;  // 65792 > A-tile's 16896

typedef unsigned short u16;
typedef unsigned int u32;
typedef unsigned long long u64;
typedef __attribute__((ext_vector_type(8))) short bf16x8;
typedef __attribute__((ext_vector_type(4))) float f32x4;

__device__ __forceinline__ u16 f2bf(float f) {   // RNE f32 -> bf16
    u32 u = __builtin_bit_cast(u32, f);
    return (u16)((u + 0x7FFFu + ((u >> 16) & 1u)) >> 16);
}

// proj (f32 [DIM][K]) -> bf16 MFMA fragment order: chunk idx = (ntile*KS+kstep)*64+lane
template<int K>
__device__ __forceinline__ void cvt_body(int idx, const float* __restrict__ src,
                                         u16* __restrict__ dst) {
    constexpr int KS = K / 32;
    int lane = idx & 63;
    int rest = idx >> 6;
    int kstep = rest % KS;
    int ntile = rest / KS;
    int n = ntile * 16 + (lane & 15);
    int k = kstep * 32 + (lane >> 4) * 8;
    const float4* p = (const float4*)(src + (size_t)n * K + k);
    float4 a = p[0], b = p[1];
    u16 t[8] = {f2bf(a.x), f2bf(a.y), f2bf(a.z), f2bf(a.w),
                f2bf(b.x), f2bf(b.y), f2bf(b.z), f2bf(b.w)};
    *(int4*)(dst + (size_t)idx * 8) = *(const int4*)t;
}

__global__ __launch_bounds__(512) void cvt_k(const float* __restrict__ proj1,
        const float* __restrict__ proj2, u16* __restrict__ projL1,
        u16* __restrict__ projL2) {
    int b = blockIdx.x;
    int tid = threadIdx.x;
    if (b < 64) cvt_body<K1>(b * 512 + tid, proj1, projL1);
    else        cvt_body<K2>((b - 64) * 512 + tid, proj2, projL2);
}

// one 32-token MFMA subtile (r12 structure, list-indirected).
// 8 waves; wave w owns n-tiles [w*8,w*8+8) x 2 m-tiles -> acc[2][8] = 64 AGPR.
// A in LDS bf16 (stride K+8, benign 2-way alias); B from fragment-ordered bf16
// (1KB coalesced wave reads, L2-resident). C staged per-m-half through LDS ->
// coalesced 4KB-row float4 stores.
template<int K>
__device__ __forceinline__ void gemm_sub(int nvalid, const u16* __restrict__ lst,
        const int* __restrict__ s_id, int tok0, int base,
        const float* __restrict__ emb, const u16* __restrict__ projL,
        float* __restrict__ out, char* __restrict__ sm) {
    constexpr int K8 = K / 8;
    constexpr int KS = K / 32;
    constexpr int LROW = K + 8;
    u16* A = (u16*)sm;
    float* Cs = (float*)sm;
    int tid = threadIdx.x;

    // stage A: 32 rows x K f32 -> bf16 (rows >= nvalid or pad row -> zeros)
    for (int c = tid; c < 32 * K8; c += 512) {
        int m = c / K8, k8 = c % K8;
        float4 v0 = make_float4(0.f,0.f,0.f,0.f), v1 = v0;
        if (m < nvalid) {
            int loc = s_id[lst[m]] - base;       // in range by construction
            if (loc != PAD) {
                const float4* p = (const float4*)(emb + (size_t)loc * K) + k8 * 2;
                v0 = p[0]; v1 = p[1];
            }
        }
        u16 t[8] = {f2bf(v0.x), f2bf(v0.y), f2bf(v0.z), f2bf(v0.w),
                    f2bf(v1.x), f2bf(v1.y), f2bf(v1.z), f2bf(v1.w)};
        *(int4*)&A[m * LROW + k8 * 8] = *(const int4*)t;
    }
    __syncthreads();

    int wave = tid >> 6;
    int lane = tid & 63;
    int lr = lane & 15;
    int lk = (lane >> 4) * 8;
    const bf16x8* Bfrag = (const bf16x8*)projL;

    f32x4 acc[2][8] = {};
    for (int ks = 0; ks < KS; ++ks) {
        bf16x8 a0 = *(const bf16x8*)&A[lr * LROW + ks * 32 + lk];
        bf16x8 a1 = *(const bf16x8*)&A[(16 + lr) * LROW + ks * 32 + lk];
        #pragma unroll
        for (int nt = 0; nt < 8; ++nt) {
            bf16x8 bb = Bfrag[((size_t)((wave * 8 + nt) * KS + ks)) * 64 + lane];
            acc[0][nt] = __builtin_amdgcn_mfma_f32_16x16x32_bf16(a0, bb, acc[0][nt], 0, 0, 0);
            acc[1][nt] = __builtin_amdgcn_mfma_f32_16x16x32_bf16(a1, bb, acc[1][nt], 0, 0, 0);
        }
    }
    __syncthreads();     // A dead; reuse smem as C-tile

    // C/D layout (m89): col = lane&15, row-within-tile = (lane>>4)*4 + reg.
    int rbase = (lane >> 4) * 4;
    #pragma unroll
    for (int mh = 0; mh < 2; ++mh) {
        #pragma unroll
        for (int nt = 0; nt < 8; ++nt) {
            #pragma unroll
            for (int r = 0; r < 4; ++r)
                Cs[(rbase + r) * CROW + wave * 128 + nt * 16 + lr] = acc[mh][nt][r];
        }
        __syncthreads();
        #pragma unroll
        for (int k = 0; k < 8; ++k) {
            int idx = k * 512 + tid;         // f4 index in 16x256 tile
            int row = idx >> 8;
            int col4 = idx & 255;
            int trow = mh * 16 + row;
            if (trow < nvalid) {
                const float* s = &Cs[row * CROW + col4 * 4];
                float4 v = make_float4(s[0], s[1], s[2], s[3]);
                *(float4*)(out + (size_t)(tok0 + lst[trow]) * DIM + col4 * 4) = v;
            }
        }
        __syncthreads();
    }
}

__global__ __launch_bounds__(512, 4) void mega_k(const int* __restrict__ ids,
        const float* __restrict__ emb0, const float* __restrict__ emb1,
        const float* __restrict__ emb2, const u16* __restrict__ projL1,
        const u16* __restrict__ projL2, float* __restrict__ out) {
    __shared__ __align__(16) char smem[SMEM_BYTES];
    __shared__ u16 s_list[3][TPB];
    __shared__ int s_id[TPB];
    __shared__ int s_cnt[3];
    int tid = threadIdx.x;
    int tok0 = blockIdx.x * TPB;

    if (tid < 3) s_cnt[tid] = 0;
    if (tid < TPB) s_id[tid] = ids[tok0 + tid];
    __syncthreads();
    if (tid < TPB) {
        int id = s_id[tid];
        int c = (id >= C2) ? 2 : ((id >= C1) ? 1 : 0);
        int pos = atomicAdd(&s_cnt[c], 1);      // LDS atomic; order-free result
        s_list[c][pos] = (u16)tid;
    }
    __syncthreads();
    int n0 = s_cnt[0], n1 = s_cnt[1], n2 = s_cnt[2];

    // cluster-0 copy: 2 rows per iteration (512 threads = 2 x 256 float4)
    {
        const float4* e4 = (const float4*)emb0;
        float4* o4 = (float4*)out;
        int half = tid >> 8;                    // 0 or 1
        int d4 = tid & 255;
        for (int i = half; i < n0; i += 2) {
            int lt = s_list[0][i];
            int id = s_id[lt];
            float4 v = make_float4(0.f, 0.f, 0.f, 0.f);
            if (id != PAD) v = e4[(size_t)id * 256 + d4];
            o4[(size_t)(tok0 + lt) * 256 + d4] = v;
        }
    }

    // cluster-1 / cluster-2 MFMA subtiles
    for (int s = 0; s * 32 < n1; ++s)
        gemm_sub<K1>(min(32, n1 - s * 32), &s_list[1][s * 32], s_id, tok0, C1,
                     emb1, projL1, out, smem);
    for (int s = 0; s * 32 < n2; ++s)
        gemm_sub<K2>(min(32, n2 - s * 32), &s_list[2][s * 32], s_id, tok0, C2,
                     emb2, projL2, out, smem);
}

extern "C" void kernel_launch(void* const* d_in, const int* in_sizes, int n_in,
                              void* d_out, int out_size, void* d_ws, size_t ws_size,
                              hipStream_t stream) {
    const int*   ids   = (const int*)d_in[0];
    const float* emb0  = (const float*)d_in[1];
    const float* emb1  = (const float*)d_in[2];
    const float* emb2  = (const float*)d_in[3];
    const float* proj1 = (const float*)d_in[4];
    const float* proj2 = (const float*)d_in[5];
    float* out = (float*)d_out;

    u16* projL1 = (u16*)d_ws;                    // fragment-ordered bf16 panels
    u16* projL2 = projL1 + NP1;

    cvt_k<<<80, 512, 0, stream>>>(proj1, proj2, projL1, projL2);
    mega_k<<<NBLK, 512, 0, stream>>>(ids, emb0, emb1, emb2, projL1, projL2, out);
}

// Round 14
// 53.405 us; speedup vs baseline: 4.8546x; 4.8546x over previous
//
#include <hip/hip_runtime.h>

// AdaptiveEmbedding: VOCAB=50000, cutoffs [20000,40000], EMBED_DIM=1024, pad=1
// cluster 0: ids [0,20000)     -> emb0 [20000,1024], direct f32 gather
// cluster 1: ids [20000,40000) -> emb1 [20000,256]  @ proj1[1024,256]^T  (bf16 MFMA)
// cluster 2: ids [40000,50000) -> emb2 [10000,64]   @ proj2[1024,64]^T   (bf16 MFMA)
//
// prep_k: classify + proj->bf16 fragment converts.
// fused_k (r12 champion): 512-thread blocks, gemm C staged through 66KB LDS ->
// coalesced 4KB-row float4 stores; plain loads/stores (NT refuted r12, NT
// loads implicated in r11 regression). THIS ROUND (single variable): stripe
// role rotation (b + b/6) % 6 — plain b%6 vs XCD=b%8 share factor 2, pinning
// gemm1 to even XCDs and gemm2 to odd; rotation covers all (XCD, role) pairs.

constexpr int NTOK = 8 * 4096;
constexpr int C1 = 20000;
constexpr int C2 = 40000;
constexpr int DIM = 1024;
constexpr int PAD = 1;
constexpr int K1 = 256, K2 = 64;
constexpr int NP1 = DIM * K1;
constexpr int NP2 = DIM * K2;
constexpr int GTOK = 32;             // tokens per gemm block
constexpr int NB1 = NTOK / GTOK;     // 1024 stripes
constexpr int CROW = DIM + 4;        // C-tile row stride (words): 2-way alias only
constexpr int SMEM_BYTES = 16 * CROW * 4;  // 65792 > A-tile's 16896

typedef unsigned short u16;
typedef unsigned int u32;
typedef unsigned long long u64;
typedef __attribute__((ext_vector_type(8))) short bf16x8;
typedef __attribute__((ext_vector_type(4))) float f32x4;

__device__ __forceinline__ u16 f2bf(float f) {   // RNE f32 -> bf16
    u32 u = __builtin_bit_cast(u32, f);
    return (u16)((u + 0x7FFFu + ((u >> 16) & 1u)) >> 16);
}

// proj (f32 [DIM][K]) -> bf16 MFMA fragment order: chunk idx = (ntile*KS+kstep)*64+lane
template<int K>
__device__ __forceinline__ void cvt_body(int idx, const float* __restrict__ src,
                                         u16* __restrict__ dst) {
    constexpr int KS = K / 32;
    int lane = idx & 63;
    int rest = idx >> 6;
    int kstep = rest % KS;
    int ntile = rest / KS;
    int n = ntile * 16 + (lane & 15);
    int k = kstep * 32 + (lane >> 4) * 8;
    const float4* p = (const float4*)(src + (size_t)n * K + k);
    float4 a = p[0], b = p[1];
    u16 t[8] = {f2bf(a.x), f2bf(a.y), f2bf(a.z), f2bf(a.w),
                f2bf(b.x), f2bf(b.y), f2bf(b.z), f2bf(b.w)};
    *(int4*)(dst + (size_t)idx * 8) = *(const int4*)t;
}

// blocks 0..63: compaction (one global atomic per list per block);
// blocks 64..127: cvt proj1; blocks 128..143: cvt proj2
__global__ __launch_bounds__(512) void prep_k(const int* __restrict__ ids,
        u16* __restrict__ list1, u16* __restrict__ list2, int* __restrict__ counters,
        const float* __restrict__ proj1, const float* __restrict__ proj2,
        u16* __restrict__ projL1, u16* __restrict__ projL2) {
    int b = blockIdx.x;
    int tid = threadIdx.x;
    if (b >= 64) {
        if (b < 128) cvt_body<K1>((b - 64) * 512 + tid, proj1, projL1);
        else         cvt_body<K2>((b - 128) * 512 + tid, proj2, projL2);
        return;
    }
    __shared__ int woff1[8], woff2[8];
    __shared__ int base1, base2;
    int i = b * 512 + tid;
    int id = ids[i];
    bool in1 = (id >= C1) & (id < C2);
    bool in2 = (id >= C2);
    u64 b1 = __ballot(in1);
    u64 b2 = __ballot(in2);
    int wave = tid >> 6, lane = tid & 63;
    if (lane == 0) { woff1[wave] = __popcll(b1); woff2[wave] = __popcll(b2); }
    __syncthreads();
    if (tid == 0) {
        int t1 = 0, t2 = 0;
        #pragma unroll
        for (int w = 0; w < 8; ++w) {
            int c1 = woff1[w]; woff1[w] = t1; t1 += c1;
            int c2 = woff2[w]; woff2[w] = t2; t2 += c2;
        }
        base1 = atomicAdd(&counters[0], t1);
        base2 = atomicAdd(&counters[16], t2);
    }
    __syncthreads();
    u64 lt = (lane == 63) ? ~0ull >> 1 : (1ull << lane) - 1;
    if (in1) list1[base1 + woff1[wave] + __popcll(b1 & lt)] = (u16)i;
    if (in2) list2[base2 + woff2[wave] + __popcll(b2 & lt)] = (u16)i;
}

// gemm: 32 tokens x 1024 outputs per block, 8 waves; wave w owns n-tiles
// [w*8, w*8+8) x 2 m-tiles -> acc[2][8] = 64 AGPR. A in LDS bf16 (stride K+8).
// B from fragment-ordered bf16 (1KB coalesced wave reads, L2-resident).
// C staged per-m-half through LDS -> coalesced 4KB-row float4 stores.
template<int K>
__device__ __forceinline__ void gemm_body(int b, const int* __restrict__ ids,
        const float* __restrict__ emb, const u16* __restrict__ projL,
        const u16* __restrict__ list, const int* __restrict__ count_ptr,
        int base, float* __restrict__ out,
        char* __restrict__ sm, u16* __restrict__ s_tok, int* __restrict__ s_loc) {
    constexpr int K8 = K / 8;
    constexpr int KS = K / 32;
    constexpr int LROW = K + 8;
    u16* A = (u16*)sm;
    float* Cs = (float*)sm;
    int count = *count_ptr;
    int t0 = b * GTOK;
    if (t0 >= count) return;
    int nt_valid = min(GTOK, count - t0);
    int tid = threadIdx.x;

    if (tid < GTOK) {
        int tokidx = 0, loc = -1;
        if (tid < nt_valid) {
            tokidx = list[t0 + tid];
            loc = ids[tokidx] - base;
            if (loc == PAD) loc = -1;            // padding row -> zeros
        }
        s_tok[tid] = (u16)tokidx;
        s_loc[tid] = loc;
    }
    __syncthreads();

    for (int c = tid; c < GTOK * K8; c += 512) {
        int m = c / K8, k8 = c % K8;
        int loc = s_loc[m];
        float4 v0 = make_float4(0.f,0.f,0.f,0.f), v1 = v0;
        if (loc >= 0) {
            const float4* p = (const float4*)(emb + (size_t)loc * K) + k8 * 2;
            v0 = p[0]; v1 = p[1];
        }
        u16 t[8] = {f2bf(v0.x), f2bf(v0.y), f2bf(v0.z), f2bf(v0.w),
                    f2bf(v1.x), f2bf(v1.y), f2bf(v1.z), f2bf(v1.w)};
        *(int4*)&A[m * LROW + k8 * 8] = *(const int4*)t;
    }
    __syncthreads();

    int wave = tid >> 6;
    int lane = tid & 63;
    int lr = lane & 15;
    int lk = (lane >> 4) * 8;
    const bf16x8* Bfrag = (const bf16x8*)projL;

    f32x4 acc[2][8] = {};
    for (int ks = 0; ks < KS; ++ks) {
        bf16x8 a0 = *(const bf16x8*)&A[lr * LROW + ks * 32 + lk];
        bf16x8 a1 = *(const bf16x8*)&A[(16 + lr) * LROW + ks * 32 + lk];
        #pragma unroll
        for (int nt = 0; nt < 8; ++nt) {
            bf16x8 bb = Bfrag[((size_t)((wave * 8 + nt) * KS + ks)) * 64 + lane];
            acc[0][nt] = __builtin_amdgcn_mfma_f32_16x16x32_bf16(a0, bb, acc[0][nt], 0, 0, 0);
            acc[1][nt] = __builtin_amdgcn_mfma_f32_16x16x32_bf16(a1, bb, acc[1][nt], 0, 0, 0);
        }
    }
    __syncthreads();     // A dead; reuse smem as C-tile

    // C/D layout (m89): col = lane&15, row-within-tile = (lane>>4)*4 + reg.
    int rbase = (lane >> 4) * 4;
    #pragma unroll
    for (int mh = 0; mh < 2; ++mh) {
        // scatter this m-half's 16x1024 tile into LDS (2-way bank alias only)
        #pragma unroll
        for (int nt = 0; nt < 8; ++nt) {
            #pragma unroll
            for (int r = 0; r < 4; ++r)
                Cs[(rbase + r) * CROW + wave * 128 + nt * 16 + lr] = acc[mh][nt][r];
        }
        __syncthreads();
        // stream out as coalesced 4KB rows (plain float4 stores)
        #pragma unroll
        for (int k = 0; k < 8; ++k) {
            int idx = k * 512 + tid;         // f4 index in 16x256 tile
            int row = idx >> 8;
            int col4 = idx & 255;
            int trow = mh * 16 + row;
            if (trow < nt_valid) {
                const float* s = &Cs[row * CROW + col4 * 4];
                float4 v = make_float4(s[0], s[1], s[2], s[3]);
                *(float4*)(out + (size_t)s_tok[trow] * DIM + col4 * 4) = v;
            }
        }
        __syncthreads();
    }
}

__global__ __launch_bounds__(512, 4) void fused_k(const int* __restrict__ ids,
        const float* __restrict__ emb0, const float* __restrict__ emb1,
        const float* __restrict__ emb2, const u16* __restrict__ projL1,
        const u16* __restrict__ projL2, const u16* __restrict__ list1,
        const u16* __restrict__ list2, const int* __restrict__ counters,
        float* __restrict__ out) {
    __shared__ __align__(16) char smem[SMEM_BYTES];
    __shared__ u16 s_tok[GTOK];
    __shared__ int s_loc[GTOK];
    // stripe of 6 with per-stripe rotation: period lcm(48,8) covers every
    // (XCD, role) pair; each stripe still holds each role exactly once.
    int b = blockIdx.x;
    int stripe = b / 6;
    int role = (b + stripe) % 6;
    if (role == 0) {
        gemm_body<K1>(stripe, ids, emb1, projL1, list1, &counters[0], C1, out, smem, s_tok, s_loc);
        return;
    }
    if (role == 1) {
        gemm_body<K2>(stripe, ids, emb2, projL2, list2, &counters[16], C2, out, smem, s_tok, s_loc);
        return;
    }
    // cluster 0 copy: 8 tokens per block, 512 threads x 4 float4 each
    int cb = stripe * 4 + (role - 2);
    int tbase = cb * 8;
    int tid = threadIdx.x;
    const float4* e4 = (const float4*)emb0;
    float4* o4 = (float4*)out;
    #pragma unroll
    for (int r = 0; r < 4; ++r) {
        int j = r * 512 + tid;          // float4 index within the 8 rows
        int tok = tbase + (j >> 8);     // 256 float4 per row
        int d4 = j & 255;
        int id = ids[tok];
        if (id < C1) {
            float4 v = make_float4(0.f, 0.f, 0.f, 0.f);
            if (id != PAD) v = e4[(size_t)id * 256 + d4];
            o4[(size_t)tok * 256 + d4] = v;
        }
    }
}

extern "C" void kernel_launch(void* const* d_in, const int* in_sizes, int n_in,
                              void* d_out, int out_size, void* d_ws, size_t ws_size,
                              hipStream_t stream) {
    const int*   ids   = (const int*)d_in[0];
    const float* emb0  = (const float*)d_in[1];
    const float* emb1  = (const float*)d_in[2];
    const float* emb2  = (const float*)d_in[3];
    const float* proj1 = (const float*)d_in[4];
    const float* proj2 = (const float*)d_in[5];
    float* out = (float*)d_out;

    int* counters = (int*)d_ws;                          // [0]=count1, [16]=count2
    u16* list1  = (u16*)((char*)d_ws + 128);
    u16* list2  = list1 + NTOK;
    u16* projL1 = list2 + NTOK;                          // fragment-ordered bf16
    u16* projL2 = projL1 + NP1;

    hipMemsetAsync(d_ws, 0, 128, stream);                // reset counters every call
    prep_k<<<144, 512, 0, stream>>>(ids, list1, list2, counters,
                                    proj1, proj2, projL1, projL2);
    fused_k<<<NB1 * 6, 512, 0, stream>>>(ids, emb0, emb1, emb2,
                                         projL1, projL2, list1, list2,
                                         counters, out);
}

// Round 15
// 51.871 us; speedup vs baseline: 4.9982x; 1.0296x over previous
//
#include <hip/hip_runtime.h>

// AdaptiveEmbedding: VOCAB=50000, cutoffs [20000,40000], EMBED_DIM=1024, pad=1
// cluster 0: ids [0,20000)     -> emb0 [20000,1024], direct f32 gather
// cluster 1: ids [20000,40000) -> emb1 [20000,256]  @ proj1[1024,256]^T  (bf16 MFMA)
// cluster 2: ids [40000,50000) -> emb2 [10000,64]   @ proj2[1024,64]^T   (bf16 MFMA)
//
// prep_k: ATOMIC-FREE classify (per-block segmented lists + plain-stored
// counts; no memset node, graph = 2 dispatches) + proj->bf16 cvt.
// fused_k (r14 champion): stripe [g1,g2,c,c,c,c] with per-stripe role
// rotation (XCD balance, r14: -12%); gemm C staged through 66KB LDS ->
// coalesced 4KB-row float4 stores; plain loads/stores. Gemm blocks rebuild
// the global list order via 64-wide shfl prefix scan + binary search.

constexpr int NTOK = 8 * 4096;
constexpr int C1 = 20000;
constexpr int C2 = 40000;
constexpr int DIM = 1024;
constexpr int PAD = 1;
constexpr int K1 = 256, K2 = 64;
constexpr int NP1 = DIM * K1;
constexpr int NP2 = DIM * K2;
constexpr int GTOK = 32;             // tokens per gemm block
constexpr int NB1 = NTOK / GTOK;     // 1024 stripes
constexpr int NSEG = 64;             // classify blocks / list segments
constexpr int SEGW = 512;            // tokens per segment
constexpr int CROW = DIM + 4;        // C-tile row stride (words): 2-way alias only
constexpr int SMEM_BYTES = 16 * CROW * 4;  // 65792 > A-tile's 16896

typedef unsigned short u16;
typedef unsigned int u32;
typedef unsigned long long u64;
typedef __attribute__((ext_vector_type(8))) short bf16x8;
typedef __attribute__((ext_vector_type(4))) float f32x4;

__device__ __forceinline__ u16 f2bf(float f) {   // RNE f32 -> bf16
    u32 u = __builtin_bit_cast(u32, f);
    return (u16)((u + 0x7FFFu + ((u >> 16) & 1u)) >> 16);
}

// proj (f32 [DIM][K]) -> bf16 MFMA fragment order: chunk idx = (ntile*KS+kstep)*64+lane
template<int K>
__device__ __forceinline__ void cvt_body(int idx, const float* __restrict__ src,
                                         u16* __restrict__ dst) {
    constexpr int KS = K / 32;
    int lane = idx & 63;
    int rest = idx >> 6;
    int kstep = rest % KS;
    int ntile = rest / KS;
    int n = ntile * 16 + (lane & 15);
    int k = kstep * 32 + (lane >> 4) * 8;
    const float4* p = (const float4*)(src + (size_t)n * K + k);
    float4 a = p[0], b = p[1];
    u16 t[8] = {f2bf(a.x), f2bf(a.y), f2bf(a.z), f2bf(a.w),
                f2bf(b.x), f2bf(b.y), f2bf(b.z), f2bf(b.w)};
    *(int4*)(dst + (size_t)idx * 8) = *(const int4*)t;
}

// blocks 0..63: per-segment compaction, NO global atomics (counts plain-stored);
// blocks 64..127: cvt proj1; blocks 128..143: cvt proj2
__global__ __launch_bounds__(512) void prep_k(const int* __restrict__ ids,
        u16* __restrict__ list1, u16* __restrict__ list2,
        int* __restrict__ cnt1, int* __restrict__ cnt2,
        const float* __restrict__ proj1, const float* __restrict__ proj2,
        u16* __restrict__ projL1, u16* __restrict__ projL2) {
    int b = blockIdx.x;
    int tid = threadIdx.x;
    if (b >= 64) {
        if (b < 128) cvt_body<K1>((b - 64) * 512 + tid, proj1, projL1);
        else         cvt_body<K2>((b - 128) * 512 + tid, proj2, projL2);
        return;
    }
    __shared__ int woff1[8], woff2[8];
    int i = b * SEGW + tid;
    int id = ids[i];
    bool in1 = (id >= C1) & (id < C2);
    bool in2 = (id >= C2);
    u64 b1 = __ballot(in1);
    u64 b2 = __ballot(in2);
    int wave = tid >> 6, lane = tid & 63;
    if (lane == 0) { woff1[wave] = __popcll(b1); woff2[wave] = __popcll(b2); }
    __syncthreads();
    if (tid == 0) {
        int t1 = 0, t2 = 0;
        #pragma unroll
        for (int w = 0; w < 8; ++w) {
            int c1 = woff1[w]; woff1[w] = t1; t1 += c1;
            int c2 = woff2[w]; woff2[w] = t2; t2 += c2;
        }
        cnt1[b] = t1;                         // plain store: no init needed
        cnt2[b] = t2;
    }
    __syncthreads();
    u64 lt = (lane == 63) ? ~0ull >> 1 : (1ull << lane) - 1;
    if (in1) list1[b * SEGW + woff1[wave] + __popcll(b1 & lt)] = (u16)i;
    if (in2) list2[b * SEGW + woff2[wave] + __popcll(b2 & lt)] = (u16)i;
}

// gemm: 32 tokens x 1024 outputs per block, 8 waves; wave w owns n-tiles
// [w*8, w*8+8) x 2 m-tiles -> acc[2][8] = 64 AGPR. Token list reconstructed
// from segmented lists via prefix scan (wave 0) + binary search (first 32
// threads). A in LDS bf16 (stride K+8); B fragment-ordered bf16 (1KB
// coalesced wave reads, L2-resident). C staged per-m-half through LDS ->
// coalesced 4KB-row float4 stores.
template<int K>
__device__ __forceinline__ void gemm_body(int b, const int* __restrict__ ids,
        const float* __restrict__ emb, const u16* __restrict__ projL,
        const u16* __restrict__ list, const int* __restrict__ cnt,
        int base, float* __restrict__ out, char* __restrict__ sm,
        u16* __restrict__ s_tok, int* __restrict__ s_loc, int* __restrict__ s_pref) {
    constexpr int K8 = K / 8;
    constexpr int KS = K / 32;
    constexpr int LROW = K + 8;
    u16* A = (u16*)sm;
    float* Cs = (float*)sm;
    int t0 = b * GTOK;
    int tid = threadIdx.x;

    if (tid < 64) {                           // wave 0: inclusive scan of counts
        int c = cnt[tid];
        #pragma unroll
        for (int d = 1; d < 64; d <<= 1) {
            int y = __shfl_up(c, d);
            if ((tid & 63) >= d) c += y;
        }
        s_pref[tid + 1] = c;
        if (tid == 0) s_pref[0] = 0;
    }
    __syncthreads();
    int count = s_pref[NSEG];
    if (t0 >= count) return;
    int nt_valid = min(GTOK, count - t0);

    if (tid < GTOK) {
        int tokidx = 0, loc = -1;
        if (tid < nt_valid) {
            int g = t0 + tid;
            int lo = 0, hi = NSEG - 1;        // find seg: pref[s] <= g < pref[s+1]
            #pragma unroll
            for (int it = 0; it < 6; ++it) {
                int mid = (lo + hi + 1) >> 1;
                if (s_pref[mid] <= g) lo = mid; else hi = mid - 1;
            }
            tokidx = list[lo * SEGW + (g - s_pref[lo])];
            loc = ids[tokidx] - base;
            if (loc == PAD) loc = -1;         // padding row -> zeros
        }
        s_tok[tid] = (u16)tokidx;
        s_loc[tid] = loc;
    }
    __syncthreads();

    for (int c = tid; c < GTOK * K8; c += 512) {
        int m = c / K8, k8 = c % K8;
        int loc = s_loc[m];
        float4 v0 = make_float4(0.f,0.f,0.f,0.f), v1 = v0;
        if (loc >= 0) {
            const float4* p = (const float4*)(emb + (size_t)loc * K) + k8 * 2;
            v0 = p[0]; v1 = p[1];
        }
        u16 t[8] = {f2bf(v0.x), f2bf(v0.y), f2bf(v0.z), f2bf(v0.w),
                    f2bf(v1.x), f2bf(v1.y), f2bf(v1.z), f2bf(v1.w)};
        *(int4*)&A[m * LROW + k8 * 8] = *(const int4*)t;
    }
    __syncthreads();

    int wave = tid >> 6;
    int lane = tid & 63;
    int lr = lane & 15;
    int lk = (lane >> 4) * 8;
    const bf16x8* Bfrag = (const bf16x8*)projL;

    f32x4 acc[2][8] = {};
    for (int ks = 0; ks < KS; ++ks) {
        bf16x8 a0 = *(const bf16x8*)&A[lr * LROW + ks * 32 + lk];
        bf16x8 a1 = *(const bf16x8*)&A[(16 + lr) * LROW + ks * 32 + lk];
        #pragma unroll
        for (int nt = 0; nt < 8; ++nt) {
            bf16x8 bb = Bfrag[((size_t)((wave * 8 + nt) * KS + ks)) * 64 + lane];
            acc[0][nt] = __builtin_amdgcn_mfma_f32_16x16x32_bf16(a0, bb, acc[0][nt], 0, 0, 0);
            acc[1][nt] = __builtin_amdgcn_mfma_f32_16x16x32_bf16(a1, bb, acc[1][nt], 0, 0, 0);
        }
    }
    __syncthreads();     // A dead; reuse smem as C-tile

    // C/D layout (m89): col = lane&15, row-within-tile = (lane>>4)*4 + reg.
    int rbase = (lane >> 4) * 4;
    #pragma unroll
    for (int mh = 0; mh < 2; ++mh) {
        #pragma unroll
        for (int nt = 0; nt < 8; ++nt) {
            #pragma unroll
            for (int r = 0; r < 4; ++r)
                Cs[(rbase + r) * CROW + wave * 128 + nt * 16 + lr] = acc[mh][nt][r];
        }
        __syncthreads();
        #pragma unroll
        for (int k = 0; k < 8; ++k) {
            int idx = k * 512 + tid;         // f4 index in 16x256 tile
            int row = idx >> 8;
            int col4 = idx & 255;
            int trow = mh * 16 + row;
            if (trow < nt_valid) {
                const float* s = &Cs[row * CROW + col4 * 4];
                float4 v = make_float4(s[0], s[1], s[2], s[3]);
                *(float4*)(out + (size_t)s_tok[trow] * DIM + col4 * 4) = v;
            }
        }
        __syncthreads();
    }
}

__global__ __launch_bounds__(512, 4) void fused_k(const int* __restrict__ ids,
        const float* __restrict__ emb0, const float* __restrict__ emb1,
        const float* __restrict__ emb2, const u16* __restrict__ projL1,
        const u16* __restrict__ projL2, const u16* __restrict__ list1,
        const u16* __restrict__ list2, const int* __restrict__ cnt1,
        const int* __restrict__ cnt2, float* __restrict__ out) {
    __shared__ __align__(16) char smem[SMEM_BYTES];
    __shared__ u16 s_tok[GTOK];
    __shared__ int s_loc[GTOK];
    __shared__ int s_pref[NSEG + 1];
    // stripe of 6 with per-stripe rotation (r14: -12%): covers all (XCD, role)
    // pairs; each stripe still holds each role exactly once.
    int b = blockIdx.x;
    int stripe = b / 6;
    int role = (b + stripe) % 6;
    if (role == 0) {
        gemm_body<K1>(stripe, ids, emb1, projL1, list1, cnt1, C1, out,
                      smem, s_tok, s_loc, s_pref);
        return;
    }
    if (role == 1) {
        gemm_body<K2>(stripe, ids, emb2, projL2, list2, cnt2, C2, out,
                      smem, s_tok, s_loc, s_pref);
        return;
    }
    // cluster 0 copy: 8 tokens per block, 512 threads x 4 float4 each
    int cb = stripe * 4 + (role - 2);
    int tbase = cb * 8;
    int tid = threadIdx.x;
    const float4* e4 = (const float4*)emb0;
    float4* o4 = (float4*)out;
    #pragma unroll
    for (int r = 0; r < 4; ++r) {
        int j = r * 512 + tid;          // float4 index within the 8 rows
        int tok = tbase + (j >> 8);     // 256 float4 per row
        int d4 = j & 255;
        int id = ids[tok];
        if (id < C1) {
            float4 v = make_float4(0.f, 0.f, 0.f, 0.f);
            if (id != PAD) v = e4[(size_t)id * 256 + d4];
            o4[(size_t)tok * 256 + d4] = v;
        }
    }
}

extern "C" void kernel_launch(void* const* d_in, const int* in_sizes, int n_in,
                              void* d_out, int out_size, void* d_ws, size_t ws_size,
                              hipStream_t stream) {
    const int*   ids   = (const int*)d_in[0];
    const float* emb0  = (const float*)d_in[1];
    const float* emb1  = (const float*)d_in[2];
    const float* emb2  = (const float*)d_in[3];
    const float* proj1 = (const float*)d_in[4];
    const float* proj2 = (const float*)d_in[5];
    float* out = (float*)d_out;

    int* cnt1   = (int*)d_ws;                            // [64]
    int* cnt2   = cnt1 + NSEG;                           // [64]
    u16* list1  = (u16*)(cnt2 + NSEG);                   // [64*512] segmented
    u16* list2  = list1 + NTOK;
    u16* projL1 = list2 + NTOK;                          // fragment-ordered bf16
    u16* projL2 = projL1 + NP1;

    prep_k<<<144, 512, 0, stream>>>(ids, list1, list2, cnt1, cnt2,
                                    proj1, proj2, projL1, projL2);
    fused_k<<<NB1 * 6, 512, 0, stream>>>(ids, emb0, emb1, emb2,
                                         projL1, projL2, list1, list2,
                                         cnt1, cnt2, out);
}